// Round 1
// baseline (329.132 us; speedup 1.0000x reference)
//
#include <hip/hip_runtime.h>

#define B_    4
#define CIN   64
#define COUT  64
#define KN    16
#define NPTS  32768

// ---------------------------------------------------------------------------
// Kernel 1: features [B][Cin][N] -> ft [B][N][Cin]  (so a neighbor "column"
// of 64 channels is one contiguous, coalesced 256B segment)
// ---------------------------------------------------------------------------
__global__ __launch_bounds__(256) void transpose_feat_kernel(
    const float* __restrict__ f, float* __restrict__ ft) {
  __shared__ float tile[64][65];            // +1 pad: conflict-free transpose
  int b    = blockIdx.y;
  int n0   = blockIdx.x * 64;
  int lane = threadIdx.x & 63;
  int g    = threadIdx.x >> 6;              // 0..3
  const float* src = f + (size_t)b * CIN * NPTS + n0;
#pragma unroll
  for (int cc = 0; cc < 16; ++cc)
    tile[cc * 4 + g][lane] = src[(size_t)(cc * 4 + g) * NPTS + lane];
  __syncthreads();
  float* dst = ft + ((size_t)b * NPTS + n0) * CIN;
#pragma unroll
  for (int nn = 0; nn < 16; ++nn)
    dst[(size_t)(nn * 4 + g) * CIN + lane] = tile[lane][nn * 4 + g];
}

// ---------------------------------------------------------------------------
// Kernel 2: positions [B][3][N] -> pt [B][N][4] (xyz0, 16B aligned)
// ---------------------------------------------------------------------------
__global__ __launch_bounds__(256) void transpose_pos_kernel(
    const float* __restrict__ p, float4* __restrict__ pt) {
  int b = blockIdx.y;
  int n = blockIdx.x * 256 + threadIdx.x;
  const float* src = p + (size_t)b * 3 * NPTS;
  float4 v;
  v.x = src[n];
  v.y = src[NPTS + n];
  v.z = src[2 * NPTS + n];
  v.w = 0.f;
  pt[(size_t)b * NPTS + n] = v;
}

// ---------------------------------------------------------------------------
// Kernel 3: fused gather + k-contraction + 256->64 linear map.
// Block = 256 threads = 4 waves; each wave owns 16 points, wave-private LDS
// T buffer [256 rows][18 words] (stride 18 => conflict-free col writes,
// 8B-aligned float2 reads).  Phase 2: per-lane 8o x 2p register tile.
// ---------------------------------------------------------------------------
__global__ __launch_bounds__(256) void flexconv_kernel(
    const float*  __restrict__ ft,    // [B][N][64]
    const float4* __restrict__ pt,    // [B][N]
    const int*    __restrict__ nb,    // [B][16][N]
    const float*  __restrict__ wt,    // [3*64][64]  (theta, rows c'=d*64+c)
    const float*  __restrict__ wb,    // [64][64]    (bias-weight, rows c'=192+c)
    const float*  __restrict__ bias,  // [64]
    float*        __restrict__ out)   // [B][64][N]
{
  __shared__ float Tbuf[4 * 256 * 18];      // 72 KB, 18KB per wave
  const int wv   = threadIdx.x >> 6;
  const int lane = threadIdx.x & 63;
  float* T = Tbuf + wv * (256 * 18);

  const int b      = blockIdx.y;
  const int n_base = blockIdx.x * 64 + wv * 16;

  const float*  ftb = ft + (size_t)b * NPTS * CIN;
  const float4* ptb = pt + (size_t)b * NPTS;
  const int*    nbb = nb + (size_t)b * KN * NPTS;

  // ---- phase 1: T[c'] = {S0,S1,S2,fsum} per point, lane = channel ----
  for (int p = 0; p < 16; ++p) {
    const int n = n_base + p;
    const float4 ctr = ptb[n];
    float fsum = 0.f, s0 = 0.f, s1 = 0.f, s2 = 0.f;
#pragma unroll
    for (int k = 0; k < KN; ++k) {
      const int idx  = nbb[(size_t)k * NPTS + n];      // wave-uniform
      const float fv = ftb[(size_t)idx * CIN + lane];  // coalesced 256B
      const float4 q = ptb[idx];                       // broadcast 16B
      fsum += fv;
      s0 += fv * (q.x - ctr.x);
      s1 += fv * (q.y - ctr.y);
      s2 += fv * (q.z - ctr.z);
    }
    T[(      lane) * 18 + p] = s0;
    T[( 64 + lane) * 18 + p] = s1;
    T[(128 + lane) * 18 + p] = s2;
    T[(192 + lane) * 18 + p] = fsum;
  }
  // wave-private LDS: same-wave RAW is ordered via compiler lgkmcnt waits;
  // no __syncthreads needed.

  // ---- phase 2: out[o, p] = sum_c' T[c',p] * W[c',o] + bias[o] ----
  const int oi = lane >> 3;   // 8 output groups of 8
  const int pi = lane & 7;    // 8 point-pairs of 2
  float acc[8][2];
#pragma unroll
  for (int a = 0; a < 8; ++a) {
    const float bv = bias[oi * 8 + a];
    acc[a][0] = bv; acc[a][1] = bv;
  }

  const float* Trd = T + pi * 2;

  auto gemm_seg = [&](const float* __restrict__ W, int c0, int rows) {
#pragma unroll 4
    for (int r = 0; r < rows; ++r) {
      const float2 t  = *(const float2*)(Trd + (c0 + r) * 18);
      const float* wp = W + (size_t)r * 64 + oi * 8;
      const float4 w0 = *(const float4*)wp;
      const float4 w1 = *(const float4*)(wp + 4);
      acc[0][0] += w0.x * t.x;  acc[0][1] += w0.x * t.y;
      acc[1][0] += w0.y * t.x;  acc[1][1] += w0.y * t.y;
      acc[2][0] += w0.z * t.x;  acc[2][1] += w0.z * t.y;
      acc[3][0] += w0.w * t.x;  acc[3][1] += w0.w * t.y;
      acc[4][0] += w1.x * t.x;  acc[4][1] += w1.x * t.y;
      acc[5][0] += w1.y * t.x;  acc[5][1] += w1.y * t.y;
      acc[6][0] += w1.z * t.x;  acc[6][1] += w1.z * t.y;
      acc[7][0] += w1.w * t.x;  acc[7][1] += w1.w * t.y;
    }
  };
  gemm_seg(wt, 0, 192);    // theta rows  c' = 0..191
  gemm_seg(wb, 192, 64);   // bias-weight c' = 192..255

  // ---- epilogue: out[b][o][n_base + pi*2 + {0,1}] ----
  float* op = out + (size_t)b * COUT * NPTS + n_base + pi * 2;
#pragma unroll
  for (int a = 0; a < 8; ++a) {
    *(float2*)&op[(size_t)(oi * 8 + a) * NPTS] = make_float2(acc[a][0], acc[a][1]);
  }
}

// ---------------------------------------------------------------------------
extern "C" void kernel_launch(void* const* d_in, const int* in_sizes, int n_in,
                              void* d_out, int out_size, void* d_ws, size_t ws_size,
                              hipStream_t stream) {
  const float* features = (const float*)d_in[0];   // [B][64][N]
  const float* wt       = (const float*)d_in[1];   // [3][64][64]
  const float* wb       = (const float*)d_in[2];   // [64][64]
  const float* bias     = (const float*)d_in[3];   // [64]
  const int*   nb       = (const int*)  d_in[4];   // [B][16][N]
  const float* pos      = (const float*)d_in[5];   // [B][3][N]
  float* out = (float*)d_out;

  float*  ft = (float*)d_ws;                                            // 33.5 MB
  float4* pt = (float4*)((char*)d_ws + (size_t)B_ * NPTS * CIN * 4);    // +2 MB

  dim3 gt(NPTS / 64, B_);
  transpose_feat_kernel<<<gt, 256, 0, stream>>>(features, ft);
  dim3 gp(NPTS / 256, B_);
  transpose_pos_kernel<<<gp, 256, 0, stream>>>(pos, pt);
  dim3 gm(NPTS / 64, B_);
  flexconv_kernel<<<gm, 256, 0, stream>>>(ft, pt, nb, wt, wb, bias, out);
}